// Round 4
// baseline (206.441 us; speedup 1.0000x reference)
//
#include <hip/hip_runtime.h>
#include <hip/hip_fp16.h>

// GAT conv: N=100000, E=1.6M, IN_C=128, OUT_C=32, HEADS=4 (OC=128)
// Round 11:
//  - k_tile PV loop 4-deep pipelined: rows average ~16 edges, each quarter
//    owns ~4 -> the whole row's gathers issue in one burst (was 2-deep;
//    latency-bound at 3.3 TB/s, VALUBusy 38%).
//  - k_prep eliminated: each gemm block builds the augmented bf16 weight
//    table in LDS directly from W/attl/attr (W is L2-resident after the
//    first blocks; ~2us aggregate). Saves a launch + gap + Wa round-trip.
//  - fill/gemm roles interleaved (blockIdx % S == 0 -> fill): fill blocks
//    spread across all CUs/XCDs so their LDS-atomic latency hides under
//    co-resident gemm blocks (was: first 196 block slots = all fill,
//    clustered on ~65 CUs).

constexpr float NEG_SLOPE = 0.2f;
constexpr int TILE_ROWS = 64;       // rows per bucket (row>>6)
constexpr int SLAB = 2048;          // max edges per bucket staged in LDS
constexpr int EPB = 8192;           // edges per fill block
constexpr int NB_PAD = 2048;        // padded bucket count for block scan
constexpr int FBMAX = 256;          // k_tile ingest supports up to 256 fill blocks

typedef __attribute__((ext_vector_type(8))) short short8;
typedef __attribute__((ext_vector_type(4))) float f32x4;

__device__ inline short f2bf(float f) {
    unsigned u = __float_as_uint(f);
    return (short)((u + 0x7fffu + ((u >> 16) & 1u)) >> 16);
}

// Fused fill + gemm, roles interleaved on blockIdx.
// fill: per-block deterministic counting sort of 8192 edges, no global atomics.
// gemm: MFMA 128 nodes/block; augmented Wa built in LDS from W/attl/attr.
__global__ __launch_bounds__(512) void k_fg(const float* __restrict__ x,
                                            const float* __restrict__ W,
                                            const float* __restrict__ attl,
                                            const float* __restrict__ attr,
                                            const int* __restrict__ ei,
                                            __half* __restrict__ xph,
                                            float* __restrict__ l,
                                            float* __restrict__ r,
                                            unsigned int* __restrict__ slab,
                                            int* __restrict__ starts,
                                            int N, int E, int NB, int FB, int S) {
    __shared__ __align__(16) char smem[49152];   // union: fill 48KB / gemm 39.2KB
    __shared__ float s_att[256];                 // attl(128) | attr(128)
    __shared__ int s_wsum[8];
    int t = threadIdx.x;
    int lane = t & 63, wv = t >> 6;
    int b = blockIdx.x;
    bool isfill = (b % S == 0) && (b / S < FB);

    if (isfill) {
        // ------------------------- fill role -------------------------
        int* s_hist = (int*)smem;                       // 8 KB
        int* s_cur  = (int*)(smem + 8192);              // 8 KB
        unsigned int* s_stage = (unsigned int*)(smem + 16384); // 32 KB

        int fb = b / S;
        int e0 = fb * EPB;
        int ecnt = min(EPB, E - e0);
        bool full = (ecnt == EPB) && ((E & 3) == 0);

        for (int i = t; i < NB_PAD; i += 512) s_hist[i] = 0;
        __syncthreads();

        const int* rows = ei;
        const int* cols = ei + E;

        if (full) {
            const int4* r4 = (const int4*)rows + (e0 >> 2);
#pragma unroll
            for (int k = 0; k < 4; ++k) {
                int4 ra = r4[k * 512 + t];
                atomicAdd(&s_hist[ra.x >> 6], 1);
                atomicAdd(&s_hist[ra.y >> 6], 1);
                atomicAdd(&s_hist[ra.z >> 6], 1);
                atomicAdd(&s_hist[ra.w >> 6], 1);
            }
        } else {
            for (int j = t; j < ecnt; j += 512)
                atomicAdd(&s_hist[rows[e0 + j] >> 6], 1);
        }
        __syncthreads();

        int b0 = t * 4;
        int c0 = s_hist[b0], c1 = s_hist[b0 + 1], c2 = s_hist[b0 + 2], c3 = s_hist[b0 + 3];
        int p = c0 + c1 + c2 + c3;
        int v = p;
#pragma unroll
        for (int off = 1; off < 64; off <<= 1) {
            int u = __shfl_up(v, off);
            if (lane >= off) v += u;
        }
        if (lane == 63) s_wsum[wv] = v;
        __syncthreads();
        if (t == 0) {
            int run = 0;
#pragma unroll
            for (int w = 0; w < 8; ++w) { int tmp = s_wsum[w]; s_wsum[w] = run; run += tmp; }
        }
        __syncthreads();
        int base = s_wsum[wv] + (v - p);
        int e1 = base + c0, e2 = e1 + c1, e3 = e2 + c2;
        s_hist[b0] = base; s_hist[b0 + 1] = e1; s_hist[b0 + 2] = e2; s_hist[b0 + 3] = e3;
        s_cur[b0] = base;  s_cur[b0 + 1] = e1;  s_cur[b0 + 2] = e2;  s_cur[b0 + 3] = e3;
        size_t sb = (size_t)fb * (NB + 1);
        if (b0 + 0 <= NB) starts[sb + b0 + 0] = base;
        if (b0 + 1 <= NB) starts[sb + b0 + 1] = e1;
        if (b0 + 2 <= NB) starts[sb + b0 + 2] = e2;
        if (b0 + 3 <= NB) starts[sb + b0 + 3] = e3;
        __syncthreads();

        if (full) {
            const int4* r4 = (const int4*)rows + (e0 >> 2);
            const int4* c4 = (const int4*)cols + (e0 >> 2);
#pragma unroll
            for (int k = 0; k < 4; ++k) {
                int4 ra = r4[k * 512 + t];
                int4 ca = c4[k * 512 + t];
                int pos;
                pos = atomicAdd(&s_cur[ra.x >> 6], 1);
                s_stage[pos] = ((unsigned int)ca.x << 6) | (unsigned int)(ra.x & 63);
                pos = atomicAdd(&s_cur[ra.y >> 6], 1);
                s_stage[pos] = ((unsigned int)ca.y << 6) | (unsigned int)(ra.y & 63);
                pos = atomicAdd(&s_cur[ra.z >> 6], 1);
                s_stage[pos] = ((unsigned int)ca.z << 6) | (unsigned int)(ra.z & 63);
                pos = atomicAdd(&s_cur[ra.w >> 6], 1);
                s_stage[pos] = ((unsigned int)ca.w << 6) | (unsigned int)(ra.w & 63);
            }
        } else {
            for (int j = t; j < ecnt; j += 512) {
                int rr = rows[e0 + j], cc = cols[e0 + j];
                int pos = atomicAdd(&s_cur[rr >> 6], 1);
                s_stage[pos] = ((unsigned int)cc << 6) | (unsigned int)(rr & 63);
            }
        }
        __syncthreads();

        uint4* dst = (uint4*)(slab + (size_t)fb * EPB);
        const uint4* src = (const uint4*)s_stage;
        int n4 = (ecnt + 3) >> 2;
        for (int i = t; i < n4; i += 512) dst[i] = src[i];
        return;
    }

    // ------------------------- gemm role -------------------------
    // Build augmented Wa[144][136] bf16 in LDS directly from W/attl/attr:
    //   rows 0..127 = W cast; rows 128+wh (wh<4)=wl, 132+wh=wr; 136..143 = 0.
    short* s_wa = (short*)smem;     // 144 rows x 136 shorts (272B stride)
    if (t < 128)       s_att[t] = attl[t];
    else if (t < 256)  s_att[t] = attr[t - 128];
    for (int i = t; i < 128 * 128; i += 512) {
        int row = i >> 7, col = i & 127;
        s_wa[row * 136 + col] = f2bf(W[i]);
    }
    for (int i = t; i < 1024; i += 512) {
        int row = 136 + (i >> 7), col = i & 127;
        s_wa[row * 136 + col] = 0;
    }
    __syncthreads();
#pragma unroll
    for (int s = 0; s < 2; ++s) {
        int e = t + s * 512;                 // 1024 augmented entries
        int which = e >> 9;                  // 0 = l, 1 = r
        int h = (e >> 7) & 3;
        int k = e & 127;
        float acc = 0.f;
#pragma unroll 8
        for (int c = 0; c < 32; ++c)
            acc += s_att[which * 128 + h * 32 + c] * W[(h * 32 + c) * 128 + k];
        s_wa[(128 + which * 4 + h) * 136 + k] = f2bf(acc);
    }
    __syncthreads();

    int li = lane & 15, quad = lane >> 4;
    int gb = b - min((b + S - 1) / S, FB);
    int base = gb * 128 + wv * 16;

    f32x4 acc[9];
#pragma unroll
    for (int nt = 0; nt < 9; ++nt) acc[nt] = (f32x4){0.f, 0.f, 0.f, 0.f};

    int anode = base + li;
    bool avalid = anode < N;
    const float4* x4 = (const float4*)x;
    const short8* wb8 = (const short8*)s_wa;

#pragma unroll
    for (int kc = 0; kc < 4; ++kc) {
        float4 p0 = make_float4(0.f, 0.f, 0.f, 0.f), p1 = p0;
        if (avalid) {
            p0 = x4[(size_t)anode * 32 + kc * 8 + quad * 2];
            p1 = x4[(size_t)anode * 32 + kc * 8 + quad * 2 + 1];
        }
        short8 a;
        a[0] = f2bf(p0.x); a[1] = f2bf(p0.y); a[2] = f2bf(p0.z); a[3] = f2bf(p0.w);
        a[4] = f2bf(p1.x); a[5] = f2bf(p1.y); a[6] = f2bf(p1.z); a[7] = f2bf(p1.w);
#pragma unroll
        for (int nt = 0; nt < 9; ++nt) {
            short8 bfrag = wb8[(nt * 16 + li) * 17 + kc * 4 + quad];
            acc[nt] = __builtin_amdgcn_mfma_f32_16x16x32_bf16(a, bfrag, acc[nt], 0, 0, 0);
        }
    }

    // l/r columns straight to global
#pragma unroll
    for (int j = 0; j < 4; ++j) {
        int node = base + quad * 4 + j;
        if (node >= N) continue;
        if (li < 4)      l[node * 4 + li] = acc[8][j];
        else if (li < 8) r[node * 4 + li - 4] = acc[8][j];
    }

    // re-stage C through s_wa (reads of Wa done), then coalesced short8 out
    __syncthreads();
    __half* s_out = (__half*)s_wa;   // [128 nodes][136] halves, stride 272B
#pragma unroll
    for (int j = 0; j < 4; ++j) {
        int nl = wv * 16 + quad * 4 + j;
#pragma unroll
        for (int nt = 0; nt < 8; ++nt)
            s_out[nl * 136 + nt * 16 + li] = __float2half(acc[nt][j]);
    }
    __syncthreads();
    {
        int nl = t >> 2, seg = t & 3;
        int node = gb * 128 + nl;
        if (node < N) {
            const short8* sr = (const short8*)s_wa;
            short8* xp8 = (short8*)xph;
#pragma unroll
            for (int q = 0; q < 4; ++q)
                xp8[(size_t)node * 16 + seg * 4 + q] = sr[nl * 17 + seg * 4 + q];
        }
    }
}

// One block per bucket, 512 threads = 8 waves.
__global__ __launch_bounds__(512) void k_tile(const int* __restrict__ starts,
                                              const unsigned int* __restrict__ slab,
                                              const float* __restrict__ l,
                                              const float* __restrict__ r,
                                              const __half* __restrict__ xph,
                                              const float* __restrict__ bias,
                                              float* __restrict__ out,
                                              int N, int NB, int FB) {
    __shared__ unsigned int s_packed[SLAB];   // 8 KB
    __shared__ int s_col[SLAB];               // 8 KB
    __shared__ __half s_w[SLAB * 4];          // 16 KB: [pos][h]
    __shared__ float s_dsum[TILE_ROWS * 4];   // 1 KB
    __shared__ float s_l[TILE_ROWS * 4];      // 1 KB
    __shared__ int s_start[TILE_ROWS + 1];
    __shared__ int s_cursor[TILE_ROWS];
    __shared__ int s_cnt[TILE_ROWS];
    __shared__ int s_fbase[FBMAX];
    __shared__ int s_foff[FBMAX + 1];
    __shared__ int s_w4[4];

    int b = blockIdx.x;
    int base = b * TILE_ROWS;
    int t = threadIdx.x;
    int lane = t & 63, wv = t >> 6;
    int rows = min(TILE_ROWS, N - base);

    if (t < TILE_ROWS) s_cnt[t] = 0;
    if (t < rows * 4) s_l[t] = l[base * 4 + t];

    // per-fill-block run start/count for this bucket
    int myc = 0;
    if (t < FB) {
        const int* sp = starts + (size_t)t * (NB + 1) + b;
        int a0 = sp[0], a1 = sp[1];
        s_fbase[t] = a0;
        myc = a1 - a0;
    }
    int v = 0;
    if (t < 256) {
        v = myc;
#pragma unroll
        for (int off = 1; off < 64; off <<= 1) {
            int u = __shfl_up(v, off);
            if (lane >= off) v += u;
        }
        if (lane == 63) s_w4[wv] = v;
    }
    __syncthreads();
    if (t == 0) {
        int run = 0;
#pragma unroll
        for (int w = 0; w < 4; ++w) { int tmp = s_w4[w]; s_w4[w] = run; run += tmp; }
        s_foff[0] = 0;
    }
    __syncthreads();
    if (t < 256) s_foff[t + 1] = v + s_w4[wv];
    __syncthreads();
    int tot = s_foff[FB];
    if (tot > SLAB) tot = SLAB;

    // gather runs into s_packed (binary search for owning fill block)
    for (int i = t; i < tot; i += 512) {
        int lo = 0, hi = FB;
        while (hi - lo > 1) {
            int mid = (lo + hi) >> 1;
            if (s_foff[mid] <= i) lo = mid; else hi = mid;
        }
        unsigned int p = slab[(size_t)lo * EPB + s_fbase[lo] + (i - s_foff[lo])];
        s_packed[i] = p;
        atomicAdd(&s_cnt[p & 63], 1);
    }
    __syncthreads();

    // counting-sort prefix per row
    if (t < 64) {
        int c = s_cnt[t];
        int vv = c;
#pragma unroll
        for (int off = 1; off < 64; off <<= 1) {
            int u = __shfl_up(vv, off);
            if (t >= off) vv += u;
        }
        s_start[t + 1] = vv;
        if (t == 0) s_start[0] = 0;
        s_cursor[t] = vv - c;
    }
    __syncthreads();

    // scatter + alpha. Exactly <=4 slots per thread (SLAB=2048, 512 threads):
    // read all slots, issue all 4 r gathers, THEN atomics/exp/stores.
    {
        int row_[4], col_[4];
        bool val_[4];
#pragma unroll
        for (int s = 0; s < 4; ++s) {
            int i = t + s * 512;
            bool valid = i < tot;
            unsigned int p = valid ? s_packed[i] : 0u;
            row_[s] = (int)(p & 63);
            col_[s] = valid ? (int)(p >> 6) : 0;
            val_[s] = valid;
        }
        float4 rv0 = ((const float4*)r)[col_[0]];
        float4 rv1 = ((const float4*)r)[col_[1]];
        float4 rv2 = ((const float4*)r)[col_[2]];
        float4 rv3 = ((const float4*)r)[col_[3]];
#pragma unroll
        for (int s = 0; s < 4; ++s) {
            if (!val_[s]) continue;
            float4 rv = s == 0 ? rv0 : s == 1 ? rv1 : s == 2 ? rv2 : rv3;
            int row = row_[s];
            int pos = atomicAdd(&s_cursor[row], 1);
            s_col[pos] = col_[s];
            float4 lv = ((const float4*)s_l)[row];
            float w0 = lv.x + rv.x, w1 = lv.y + rv.y;
            float w2 = lv.z + rv.z, w3 = lv.w + rv.w;
            w0 = w0 >= 0.f ? w0 : NEG_SLOPE * w0;
            w1 = w1 >= 0.f ? w1 : NEG_SLOPE * w1;
            w2 = w2 >= 0.f ? w2 : NEG_SLOPE * w2;
            w3 = w3 >= 0.f ? w3 : NEG_SLOPE * w3;
            w0 = __expf(w0); w1 = __expf(w1); w2 = __expf(w2); w3 = __expf(w3);
            ((__half2*)s_w)[pos * 2]     = __floats2half2_rn(w0, w1);
            ((__half2*)s_w)[pos * 2 + 1] = __floats2half2_rn(w2, w3);
        }
    }
    __syncthreads();

    // atomic-free denominators over the row-sorted s_w: thread = (row, head)
    if (t < 256) {
        int row = t >> 2, h = t & 3;
        if (row < rows) {
            int s0 = s_start[row], s1 = s_start[row + 1];
            float d = 0.f;
            for (int i = s0; i < s1; ++i)
                d += __half2float(s_w[i * 4 + h]);
            s_dsum[t] = d;
        }
    }
    __syncthreads();

    int quarter = lane >> 4;   // edge slot within wave
    int li = lane & 15;        // channel block: fp16 chans 8li..8li+7
    int h = li >> 2;           // head of this channel block
    const float4* xp4g = (const float4*)xph;  // 16B = 8 halves

    float4 b0 = ((const float4*)bias)[2 * li];
    float4 b1 = ((const float4*)bias)[2 * li + 1];

    for (int rl = wv; rl < rows; rl += 8) {
        int s0 = s_start[rl], s1 = s_start[rl + 1];
        float a0 = 0.f, a1 = 0.f, a2 = 0.f, a3 = 0.f;
        float a4 = 0.f, a5 = 0.f, a6 = 0.f, a7 = 0.f;
        // 4-deep pipelined gather: a typical row (~16 edges, ~4 per quarter)
        // issues ALL its gathers in one burst.
        for (int i0 = s0 + quarter; i0 < s1; i0 += 16) {
            int i1 = i0 + 4, i2 = i0 + 8, i3 = i0 + 12;
            bool v1 = i1 < s1, v2 = i2 < s1, v3 = i3 < s1;
            int c0 = s_col[i0];
            int c1 = v1 ? s_col[i1] : c0;
            int c2 = v2 ? s_col[i2] : c0;
            int c3 = v3 ? s_col[i3] : c0;
            float w0 = __half2float(s_w[i0 * 4 + h]);
            float w1 = v1 ? __half2float(s_w[i1 * 4 + h]) : 0.f;
            float w2 = v2 ? __half2float(s_w[i2 * 4 + h]) : 0.f;
            float w3 = v3 ? __half2float(s_w[i3 * 4 + h]) : 0.f;
            float4 r0 = xp4g[(size_t)c0 * 16 + li];
            float4 r1 = xp4g[(size_t)c1 * 16 + li];
            float4 r2 = xp4g[(size_t)c2 * 16 + li];
            float4 r3 = xp4g[(size_t)c3 * 16 + li];
#define ACC8(raw, w)                                         \
            {                                                \
                __half2* hp = (__half2*)&(raw);              \
                float2 f0 = __half22float2(hp[0]);           \
                float2 f1 = __half22float2(hp[1]);           \
                float2 f2 = __half22float2(hp[2]);           \
                float2 f3 = __half22float2(hp[3]);           \
                a0 += (w) * f0.x; a1 += (w) * f0.y;          \
                a2 += (w) * f1.x; a3 += (w) * f1.y;          \
                a4 += (w) * f2.x; a5 += (w) * f2.y;          \
                a6 += (w) * f3.x; a7 += (w) * f3.y;          \
            }
            ACC8(r0, w0);
            ACC8(r1, w1);
            ACC8(r2, w2);
            ACC8(r3, w3);
#undef ACC8
        }
        a0 += __shfl_xor(a0, 16); a0 += __shfl_xor(a0, 32);
        a1 += __shfl_xor(a1, 16); a1 += __shfl_xor(a1, 32);
        a2 += __shfl_xor(a2, 16); a2 += __shfl_xor(a2, 32);
        a3 += __shfl_xor(a3, 16); a3 += __shfl_xor(a3, 32);
        a4 += __shfl_xor(a4, 16); a4 += __shfl_xor(a4, 32);
        a5 += __shfl_xor(a5, 16); a5 += __shfl_xor(a5, 32);
        a6 += __shfl_xor(a6, 16); a6 += __shfl_xor(a6, 32);
        a7 += __shfl_xor(a7, 16); a7 += __shfl_xor(a7, 32);
        if (quarter == 0) {
            float inv = 1.f / (s_dsum[rl * 4 + h] + 1e-16f);
            float4 o0, o1;
            o0.x = a0 * inv + b0.x; o0.y = a1 * inv + b0.y;
            o0.z = a2 * inv + b0.z; o0.w = a3 * inv + b0.w;
            o1.x = a4 * inv + b1.x; o1.y = a5 * inv + b1.y;
            o1.z = a6 * inv + b1.z; o1.w = a7 * inv + b1.w;
            ((float4*)out)[(size_t)(base + rl) * 32 + 2 * li] = o0;
            ((float4*)out)[(size_t)(base + rl) * 32 + 2 * li + 1] = o1;
        }
    }
}

extern "C" void kernel_launch(void* const* d_in, const int* in_sizes, int n_in,
                              void* d_out, int out_size, void* d_ws, size_t ws_size,
                              hipStream_t stream) {
    const float* x    = (const float*)d_in[0];
    const int*   ei   = (const int*)d_in[1];
    const float* W    = (const float*)d_in[2];
    const float* attl = (const float*)d_in[3];
    const float* attr = (const float*)d_in[4];
    const float* bias = (const float*)d_in[5];
    int N = in_sizes[0] / 128;
    int E = in_sizes[1] / 2;
    int NB = (N + TILE_ROWS - 1) / TILE_ROWS;
    int FB = (E + EPB - 1) / EPB;    // 196 for E=1.6M (k_tile supports <= FBMAX)

    char* ws = (char*)d_ws;
    __half* xph = (__half*)ws;   ws += (size_t)N * 128 * 2;          // 25.6 MB
    float* l    = (float*)ws;    ws += (size_t)N * 4 * 4;
    float* r    = (float*)ws;    ws += (size_t)N * 4 * 4;
    int* starts = (int*)ws;      ws += (size_t)FB * (NB + 1) * 4;    // 1.23 MB
    unsigned int* slab = (unsigned int*)ws; ws += (size_t)FB * EPB * 4; // 6.42 MB

    float* out = (float*)d_out;
    int GB = (N + 127) / 128;
    int TOT = FB + GB;
    int S = TOT / FB; if (S < 1) S = 1;   // fill role every S-th block

    k_fg<<<TOT, 512, 0, stream>>>(x, W, attl, attr, ei, xph, l, r, slab, starts,
                                  N, E, NB, FB, S);
    k_tile<<<NB, 512, 0, stream>>>(starts, slab, l, r, xph, bias, out, N, NB, FB);
}